// Round 10
// baseline (739.636 us; speedup 1.0000x reference)
//
#include <hip/hip_runtime.h>
#include <hip/hip_bf16.h>

// GCN: 3x GCNConv(H=64) + global mean pool + linear head.
// Round 9 -> 10: two-pass CSR build. Coarse scatter into 25K (dstblock,chunk)
// bins (packed (vi<<17)|u, L2-absorbed writes) then per-block LDS counting
// sort -> contiguous csr in [row][chunk] order + 257 bounds/block + dinv/xs
// for free. Kills the 205MB line-granular scatter (160us) and shrinks
// cnt/scan/init from 800K to 25K entries.

#define WS_ALIGN(x) (((x) + 255) & ~size_t(255))
#define NCHUNK 8
#define NB 32            // dst rows per gather block
#define RPW (NB / 4)     // rows per wave = 8
#define NBIN (NB * NCHUNK)   // 256 fine bins per block
#define USH 17
#define UMASK 0x1FFFF

// zero coarse counts/cursors, pool accumulators, csr pad
__global__ __launch_bounds__(256) void k_init0(int nc, int g, int e, int* cntc,
                                               int* cursorc, int* csr,
                                               float* gsum, float* gcnt) {
    int i = blockIdx.x * blockDim.x + threadIdx.x;
    if (i < nc) { cntc[i] = 0; cursorc[i] = 0; }
    if (i < g) { gsum[i] = 0.f; gcnt[i] = 0.f; }
    if (i < 4) csr[e + i] = 0;   // overread pad (4-wide edge groups)
}

// count per coarse (dstblock, chunk) bin
__global__ __launch_bounds__(256) void k_cnt_c(int e, int sc,
                                               const int* __restrict__ src,
                                               const int* __restrict__ dst,
                                               int* __restrict__ cntc) {
    int i = blockIdx.x * blockDim.x + threadIdx.x;
    if (i >= e) return;
    atomicAdd(&cntc[(dst[i] / NB) * NCHUNK + src[i] / sc], 1);
}

// scan1: 2048-elem tiles, 8 per thread; in-place capable
__global__ __launch_bounds__(256) void k_scan1(int n, const int* __restrict__ in,
                                               int* __restrict__ outx,
                                               int* __restrict__ psum) {
    __shared__ int sd[256];
    int tid = threadIdx.x;
    int i0 = blockIdx.x * 2048 + tid * 8;
    int a[8]; int tsum = 0;
#pragma unroll
    for (int q = 0; q < 8; ++q) { a[q] = (i0 + q < n) ? in[i0 + q] : 0; tsum += a[q]; }
    sd[tid] = tsum;
    __syncthreads();
    for (int off = 1; off < 256; off <<= 1) {
        int v = (tid >= off) ? sd[tid - off] : 0;
        __syncthreads();
        sd[tid] += v;
        __syncthreads();
    }
    int excl = sd[tid] - tsum;
#pragma unroll
    for (int q = 0; q < 8; ++q) { if (i0 + q < n) outx[i0 + q] = excl; excl += a[q]; }
    if (tid == 255) psum[blockIdx.x] = sd[255];
}

__global__ __launch_bounds__(256) void k_scan2(int nchunks, int* __restrict__ psum) {
    __shared__ int sd[256];
    int tid = threadIdx.x;
    int i0 = tid * 4;
    int a = (i0 + 0 < nchunks) ? psum[i0 + 0] : 0;
    int b = (i0 + 1 < nchunks) ? psum[i0 + 1] : 0;
    int c = (i0 + 2 < nchunks) ? psum[i0 + 2] : 0;
    int d = (i0 + 3 < nchunks) ? psum[i0 + 3] : 0;
    int tsum = a + b + c + d;
    sd[tid] = tsum;
    __syncthreads();
    for (int off = 1; off < 256; off <<= 1) {
        int v = (tid >= off) ? sd[tid - off] : 0;
        __syncthreads();
        sd[tid] += v;
        __syncthreads();
    }
    int excl = sd[tid] - tsum;
    if (i0 + 0 < nchunks) psum[i0 + 0] = excl;
    if (i0 + 1 < nchunks) psum[i0 + 1] = excl + a;
    if (i0 + 2 < nchunks) psum[i0 + 2] = excl + a + b;
    if (i0 + 3 < nchunks) psum[i0 + 3] = excl + a + b + c;
}

__global__ __launch_bounds__(256) void k_scan3(int n, int e, int* __restrict__ outx,
                                               const int* __restrict__ psum) {
    int i = blockIdx.x * blockDim.x + threadIdx.x;
    if (i < n) outx[i] += psum[i >> 11];
    if (i == n) outx[n] = e;
}

// coarse scatter: packed (vi<<17)|u into coarse-bin ranges (L2-friendly writes)
__global__ __launch_bounds__(256) void k_scatter_c(int e, int sc,
                                                   const int* __restrict__ src,
                                                   const int* __restrict__ dst,
                                                   const int* __restrict__ startsC,
                                                   int* __restrict__ cursorc,
                                                   int* __restrict__ pk) {
    int i = blockIdx.x * blockDim.x + threadIdx.x;
    if (i >= e) return;
    int u = src[i];
    int v = dst[i];
    int bin = (v / NB) * NCHUNK + u / sc;
    int pos = startsC[bin] + atomicAdd(&cursorc[bin], 1);
    pk[pos] = ((v & (NB - 1)) << USH) | u;
}

// per-block counting sort: coarse bins -> csr in [row][chunk] order (contiguous
// writes), bounds[bi][257], and dinv/xs as a by-product of the fine counts.
__global__ __launch_bounds__(256) void k_fine(int n, const int* __restrict__ startsC,
                                              const int* __restrict__ pk,
                                              const float* __restrict__ x,
                                              int* __restrict__ csr,
                                              int* __restrict__ boundsG,
                                              float* __restrict__ dinv,
                                              float* __restrict__ xs) {
    __shared__ int cs[NCHUNK + 1];
    __shared__ int cntL[NBIN + 1];
    __shared__ int sd[256];
    int bi = blockIdx.x, tid = threadIdx.x;
    if (tid <= NCHUNK) cs[tid] = startsC[bi * NCHUNK + tid];
    cntL[tid] = 0;
    if (tid == 0) cntL[NBIN] = 0;
    __syncthreads();
    int cs0 = cs[0];
    // pass A: fine counts, key = vi*8 + c
    for (int c = 0; c < NCHUNK; ++c) {
        for (int k = cs[c] + tid; k < cs[c + 1]; k += 256) {
            int vi = pk[k] >> USH;
            atomicAdd(&cntL[vi * NCHUNK + c], 1);
        }
    }
    __syncthreads();
    // block scan of 256 fine counts
    int myc = cntL[tid];
    sd[tid] = myc;
    __syncthreads();
    for (int off = 1; off < 256; off <<= 1) {
        int v = (tid >= off) ? sd[tid - off] : 0;
        __syncthreads();
        sd[tid] += v;
        __syncthreads();
    }
    int excl = sd[tid] - myc;
    boundsG[(size_t)bi * (NBIN + 1) + tid] = cs0 + excl;
    if (tid == 255) boundsG[(size_t)bi * (NBIN + 1) + NBIN] = cs0 + sd[255];
    // dinv/xs: deg(vi) = sd[vi*8+7] - (vi ? sd[vi*8-1] : 0), +1 self-loop
    if (tid < NB) {
        int v = bi * NB + tid;
        if (v < n) {
            int hi = sd[tid * NCHUNK + NCHUNK - 1];
            int lo = (tid > 0) ? sd[tid * NCHUNK - 1] : 0;
            float di = 1.0f / sqrtf((float)(hi - lo + 1));
            dinv[v] = di;
            xs[v] = x[v] * di;
        }
    }
    __syncthreads();
    cntL[tid] = excl;   // relative cursor
    __syncthreads();
    // pass C: scatter into contiguous block range
    for (int c = 0; c < NCHUNK; ++c) {
        for (int k = cs[c] + tid; k < cs[c + 1]; k += 256) {
            int w = pk[k];
            int vi = w >> USH;
            int pos = atomicAdd(&cntL[vi * NCHUNK + c], 1);
            csr[cs0 + pos] = w & UMASK;
        }
    }
}

// layer 1 scalar gather, thread-per-row: s[v] = (sum xs[u] + xs[v]) * dinv[v]
__global__ __launch_bounds__(256) void k_s(int n, const int* __restrict__ boundsG,
                                           const int* __restrict__ csr,
                                           const float* __restrict__ xs,
                                           const float* __restrict__ dinv,
                                           float* __restrict__ s) {
    int v = blockIdx.x * blockDim.x + threadIdx.x;
    if (v >= n) return;
    int bi = v / NB, vi = v & (NB - 1);
    const int* B = &boundsG[(size_t)bi * (NBIN + 1)];
    int s0 = B[vi * NCHUNK];
    int s1 = B[vi * NCHUNK + NCHUNK];   // row's range contiguous in [row][chunk]
    float a0 = 0.f, a1 = 0.f, a2 = 0.f, a3 = 0.f;
    int k = s0;
    for (; k + 4 <= s1; k += 4) {
        a0 += xs[csr[k]];
        a1 += xs[csr[k + 1]];
        a2 += xs[csr[k + 2]];
        a3 += xs[csr[k + 3]];
    }
    for (; k < s1; ++k) a0 += xs[csr[k]];
    s[v] = ((a0 + a1) + (a2 + a3) + xs[v]) * dinv[v];
}

// layer 1 transform: hs1 = relu(s*w1 + b1) * dinv
__global__ __launch_bounds__(256) void k_h1(int n, const float* __restrict__ s,
                                            const float* __restrict__ dinv,
                                            const float* __restrict__ w1,
                                            const float* __restrict__ b1,
                                            float* __restrict__ hs) {
    int t = blockIdx.x * blockDim.x + threadIdx.x;
    if (t >= n * 64) return;
    int i = t >> 6, j = t & 63;
    float v = fmaxf(s[i] * w1[j] + b1[j], 0.f);
    hs[t] = v * dinv[i];
}

// ---- fused chunked-gather + inline GEMM ----
#define GATHER_CORE                                                            \
    __shared__ float ws[64 * 64];                                              \
    __shared__ float rowl[4][64];                                              \
    __shared__ int bndL[NBIN + 1];                                             \
    int tid = threadIdx.x;                                                     \
    int lane = tid & 63;                                                       \
    int r = tid >> 6;                                                          \
    int v0 = blockIdx.x * NB;                                                  \
    for (int k = tid; k < 64 * 64; k += 256) ws[k] = w[k];                     \
    bndL[tid] = boundsG[(size_t)blockIdx.x * (NBIN + 1) + tid];                \
    if (tid == 0) bndL[NBIN] = boundsG[(size_t)blockIdx.x * (NBIN + 1) + NBIN];\
    float acc[RPW];                                                            \
    _Pragma("unroll")                                                          \
    for (int q = 0; q < RPW; ++q) {                                            \
        int v = v0 + q * 4 + r;                                                \
        acc[q] = (v < n) ? hs_in[(size_t)v * 64 + lane] : 0.f;                 \
    }                                                                          \
    __syncthreads();                                                           \
    for (int c = 0; c < NCHUNK; ++c) {                                         \
        _Pragma("unroll")                                                      \
        for (int t = 0; t < RPW / 2; ++t) {                                    \
            int viA = (2 * t) * 4 + r;                                         \
            int viB = (2 * t + 1) * 4 + r;                                     \
            int a0 = __builtin_amdgcn_readfirstlane(bndL[viA * NCHUNK + c]);   \
            int a1 = __builtin_amdgcn_readfirstlane(bndL[viA * NCHUNK + c + 1]);\
            int b0_ = __builtin_amdgcn_readfirstlane(bndL[viB * NCHUNK + c]);  \
            int b1_ = __builtin_amdgcn_readfirstlane(bndL[viB * NCHUNK + c + 1]);\
            int ba = a0, bb = b0_;                                             \
            while (ba < a1 || bb < b1_) {                                      \
                int remA = a1 - ba;                                            \
                int remB = b1_ - bb;                                           \
                int pa = (remA > 0) ? ba : bb;                                 \
                int pb = (remB > 0) ? bb : ba;                                 \
                int uA0 = csr[pa],     uA1 = csr[pa + 1];                      \
                int uA2 = csr[pa + 2], uA3 = csr[pa + 3];                      \
                int uB0 = csr[pb],     uB1 = csr[pb + 1];                      \
                int uB2 = csr[pb + 2], uB3 = csr[pb + 3];                      \
                float gA0 = hs_in[(size_t)uA0 * 64 + lane];                    \
                float gA1 = hs_in[(size_t)uA1 * 64 + lane];                    \
                float gA2 = hs_in[(size_t)uA2 * 64 + lane];                    \
                float gA3 = hs_in[(size_t)uA3 * 64 + lane];                    \
                float gB0 = hs_in[(size_t)uB0 * 64 + lane];                    \
                float gB1 = hs_in[(size_t)uB1 * 64 + lane];                    \
                float gB2 = hs_in[(size_t)uB2 * 64 + lane];                    \
                float gB3 = hs_in[(size_t)uB3 * 64 + lane];                    \
                if (remA >= 4) acc[2 * t] += (gA0 + gA1) + (gA2 + gA3);        \
                else if (remA > 0) {                                           \
                    acc[2 * t] += gA0;                                         \
                    if (remA > 1) acc[2 * t] += gA1;                           \
                    if (remA > 2) acc[2 * t] += gA2;                           \
                }                                                              \
                if (remB >= 4) acc[2 * t + 1] += (gB0 + gB1) + (gB2 + gB3);    \
                else if (remB > 0) {                                           \
                    acc[2 * t + 1] += gB0;                                     \
                    if (remB > 1) acc[2 * t + 1] += gB1;                       \
                    if (remB > 2) acc[2 * t + 1] += gB2;                       \
                }                                                              \
                ba += 4; bb += 4;                                              \
            }                                                                  \
        }                                                                      \
        __syncthreads();                                                       \
    }

// mid layer: hs_out = relu((acc*dinv) @ w + b) * dinv
__global__ __launch_bounds__(256, 8) void k_gg_mid(int n,
                                                   const int* __restrict__ boundsG,
                                                   const int* __restrict__ csr,
                                                   const float* __restrict__ hs_in,
                                                   const float* __restrict__ dinv,
                                                   const float* __restrict__ w,
                                                   const float* __restrict__ b,
                                                   float* __restrict__ hs_out) {
    GATHER_CORE
    float breg = b[lane];
#pragma unroll 1
    for (int q = 0; q < RPW; ++q) {
        int v = v0 + q * 4 + r;
        if (v >= n) continue;
        float dv = dinv[v];
        rowl[r][lane] = acc[q] * dv;
        float o = breg;
#pragma unroll
        for (int k = 0; k < 64; ++k) o += rowl[r][k] * ws[k * 64 + lane];
        hs_out[(size_t)v * 64 + lane] = fmaxf(o, 0.f) * dv;
    }
}

// final layer: dots[v] = relu((acc*dinv) @ w3 + b3) . fcw
__global__ __launch_bounds__(256, 8) void k_gg_final(int n,
                                                     const int* __restrict__ boundsG,
                                                     const int* __restrict__ csr,
                                                     const float* __restrict__ hs_in,
                                                     const float* __restrict__ dinv,
                                                     const float* __restrict__ w,
                                                     const float* __restrict__ b,
                                                     const float* __restrict__ fcw,
                                                     float* __restrict__ dots) {
    GATHER_CORE
    float breg = b[lane];
    float freg = fcw[lane];
#pragma unroll 1
    for (int q = 0; q < RPW; ++q) {
        int v = v0 + q * 4 + r;
        if (v >= n) continue;
        float dv = dinv[v];
        rowl[r][lane] = acc[q] * dv;
        float o = breg;
#pragma unroll
        for (int k = 0; k < 64; ++k) o += rowl[r][k] * ws[k * 64 + lane];
        float val = fmaxf(o, 0.f) * freg;
#pragma unroll
        for (int m = 32; m > 0; m >>= 1) val += __shfl_xor(val, m, 64);
        if (lane == 0) dots[v] = val;
    }
}

// pooled accumulation: LDS-binned segmented reduce over sorted batch.
__global__ __launch_bounds__(256) void k_pool(int n, const float* __restrict__ dots,
                                              const int* __restrict__ batch,
                                              float* __restrict__ gsum,
                                              float* __restrict__ gcnt) {
    __shared__ float ls[64], lc[64];
    __shared__ int gmin_s;
    int tid = threadIdx.x;
    int i0 = blockIdx.x * 1024;
    if (tid == 0) gmin_s = batch[i0];
    if (tid < 64) { ls[tid] = 0.f; lc[tid] = 0.f; }
    __syncthreads();
    int gmin = gmin_s;
#pragma unroll
    for (int c = 0; c < 4; ++c) {
        int i = i0 + c * 256 + tid;
        if (i < n) {
            int g = batch[i];
            float d = dots[i];
            int rr = g - gmin;
            if (rr < 64) {
                atomicAdd(&ls[rr], d);
                atomicAdd(&lc[rr], 1.f);
            } else {
                atomicAdd(&gsum[g], d);
                atomicAdd(&gcnt[g], 1.f);
            }
        }
    }
    __syncthreads();
    if (tid < 64 && lc[tid] != 0.f) {
        atomicAdd(&gsum[gmin + tid], ls[tid]);
        atomicAdd(&gcnt[gmin + tid], lc[tid]);
    }
}

__global__ __launch_bounds__(256) void k_out(int g, const float* __restrict__ gsum,
                                             const float* __restrict__ gcnt,
                                             const float* __restrict__ fcb,
                                             float* __restrict__ out) {
    int i = blockIdx.x * blockDim.x + threadIdx.x;
    if (i < g) out[i] = gsum[i] / fmaxf(gcnt[i], 1.f) + fcb[0];
}

extern "C" void kernel_launch(void* const* d_in, const int* in_sizes, int n_in,
                              void* d_out, int out_size, void* d_ws, size_t ws_size,
                              hipStream_t stream) {
    const float* x    = (const float*)d_in[0];
    const int*   ei   = (const int*)d_in[1];
    const int*   batch= (const int*)d_in[2];
    const float* w1   = (const float*)d_in[3];
    const float* b1   = (const float*)d_in[4];
    const float* w2   = (const float*)d_in[5];
    const float* b2   = (const float*)d_in[6];
    const float* w3   = (const float*)d_in[7];
    const float* b3   = (const float*)d_in[8];
    const float* fcw  = (const float*)d_in[9];
    const float* fcb  = (const float*)d_in[10];
    float* out = (float*)d_out;

    const int N = in_sizes[0];           // needs N < 131072 (17-bit packing)
    const int E = in_sizes[1] / 2;
    const int G = out_size;
    const int H = 64;
    const int SC = (N + NCHUNK - 1) / NCHUNK;    // src-chunk size
    const int NBLK = (N + NB - 1) / NB;          // 3125 dst blocks
    const int NC = NBLK * NCHUNK;                // 25000 coarse bins

    const int* src = ei;
    const int* dst = ei + E;

    char* p = (char*)d_ws;
    int*   startsC = (int*)p; p += WS_ALIGN(sizeof(int) * (size_t)(NC + 1));
    int*   cursorC = (int*)p; p += WS_ALIGN(sizeof(int) * (size_t)NC);
    int*   psum    = (int*)p; p += WS_ALIGN(sizeof(int) * 1024);
    int*   pkbuf   = (int*)p; p += WS_ALIGN(sizeof(int) * (size_t)E);
    int*   csr     = (int*)p; p += WS_ALIGN(sizeof(int) * ((size_t)E + 4));
    int*   boundsG = (int*)p; p += WS_ALIGN(sizeof(int) * (size_t)NBLK * (NBIN + 1));
    float* dinv    = (float*)p; p += WS_ALIGN(sizeof(float) * N);
    float* xs      = (float*)p; p += WS_ALIGN(sizeof(float) * N);
    float* sbuf    = (float*)p; p += WS_ALIGN(sizeof(float) * N);
    float* bufA    = (float*)p; p += WS_ALIGN(sizeof(float) * (size_t)N * H);
    float* bufB    = (float*)p; p += WS_ALIGN(sizeof(float) * (size_t)N * H);
    float* dots    = (float*)p; p += WS_ALIGN(sizeof(float) * N);
    float* gsum    = (float*)p; p += WS_ALIGN(sizeof(float) * G);
    float* gcnt    = (float*)p; p += WS_ALIGN(sizeof(float) * G);

    const int B = 256;
    int gridE    = (E + B - 1) / B;
    int gridG    = (G + B - 1) / B;
    int gridC    = (NC + B - 1) / B;
    int nscan    = (NC + 2047) / 2048;
    int gridS3   = (NC + 1 + B - 1) / B;
    int gridRow  = (N + B - 1) / B;
    int gridNH   = (N * H + B - 1) / B;
    int gridPool = (N + 1023) / 1024;

    k_init0<<<gridC, B, 0, stream>>>(NC, G, E, startsC, cursorC, csr, gsum, gcnt);
    k_cnt_c<<<gridE, B, 0, stream>>>(E, SC, src, dst, startsC);
    k_scan1<<<nscan, B, 0, stream>>>(NC, startsC, startsC, psum);
    k_scan2<<<1, B, 0, stream>>>(nscan, psum);
    k_scan3<<<gridS3, B, 0, stream>>>(NC, E, startsC, psum);
    k_scatter_c<<<gridE, B, 0, stream>>>(E, SC, src, dst, startsC, cursorC, pkbuf);
    k_fine<<<NBLK, B, 0, stream>>>(N, startsC, pkbuf, x, csr, boundsG, dinv, xs);
    // layer 1 (rank-1): thread-per-row gather + elementwise transform
    k_s<<<gridRow, B, 0, stream>>>(N, boundsG, csr, xs, dinv, sbuf);
    k_h1<<<gridNH, B, 0, stream>>>(N, sbuf, dinv, w1, b1, bufA);
    // layer 2: fused gather + GEMM(w2) -> bufB
    k_gg_mid<<<NBLK, B, 0, stream>>>(N, boundsG, csr, bufA, dinv, w2, b2, bufB);
    // layer 3: fused gather + GEMM(w3) + fc dot -> dots
    k_gg_final<<<NBLK, B, 0, stream>>>(N, boundsG, csr, bufB, dinv, w3, b3, fcw, dots);
    // pooling + head
    k_pool<<<gridPool, B, 0, stream>>>(N, dots, batch, gsum, gcnt);
    k_out<<<gridG, B, 0, stream>>>(G, gsum, gcnt, fcb, out);
}

// Round 11
// 458.294 us; speedup vs baseline: 1.6139x; 1.6139x over previous
//
#include <hip/hip_runtime.h>
#include <hip/hip_bf16.h>

// GCN: 3x GCNConv(H=64) + global mean pool + linear head.
// Round 10 -> 11: line-granularity-aware CSR build.
//  p1: per-2048-edge-tile LDS sort by superblock (dst>>9), contiguous run
//      writes of packed (dstLow<<17|src) words (kills the 203MB
//      cross-XCD line-granular scatter).
//  p2: one block per superblock (512 dsts) counting-sorts its contiguous
//      bucket into [row][chunk] csr order; block solely owns its csr region
//      (single-XCD -> L2 merges writes). Emits bounds + dinv/xs for free.
// Gather/GEMM-fused layer kernels unchanged from R9/R10.

#define WS_ALIGN(x) (((x) + 255) & ~size_t(255))
#define NCHUNK 8
#define NB 32            // dst rows per gather block
#define RPW (NB / 4)     // rows per wave
#define NBIN 256         // NB*NCHUNK fine bins per gather block
#define USH 17
#define UMASK 0x1FFFF
#define BKTMAX 256       // max superblocks (N <= 131072)
#define SBS 512          // dsts per superblock
#define SBKEYS 4096      // SBS * NCHUNK
#define P1T 2048         // edges per p1 tile

// zero bucket counts/cursors, pool accumulators, csr pad
__global__ __launch_bounds__(256) void k_zero(int g, int e, int* bucketCnt,
                                              int* gCursor, int* csr,
                                              float* gsum, float* gcnt) {
    int i = blockIdx.x * blockDim.x + threadIdx.x;
    if (i < BKTMAX) { bucketCnt[i] = 0; gCursor[i] = 0; }
    if (i < g) { gsum[i] = 0.f; gcnt[i] = 0.f; }
    if (i < 4) csr[e + i] = 0;
}

// per-tile LDS-aggregated superblock counts
__global__ __launch_bounds__(256) void k_cnt1(int e, const int* __restrict__ dst,
                                              int* __restrict__ bucketCnt) {
    __shared__ int c[BKTMAX];
    int tid = threadIdx.x;
    c[tid] = 0;
    __syncthreads();
    int base = blockIdx.x * P1T;
#pragma unroll
    for (int q = 0; q < P1T / 256; ++q) {
        int i = base + q * 256 + tid;
        if (i < e) atomicAdd(&c[dst[i] >> 9], 1);
    }
    __syncthreads();
    if (c[tid] > 0) atomicAdd(&bucketCnt[tid], c[tid]);
}

// single-block scan of <=256 bucket counts -> bucketStart[nbkt+1]
__global__ __launch_bounds__(256) void k_scanB(int nbkt, int e,
                                               const int* __restrict__ bucketCnt,
                                               int* __restrict__ bucketStart) {
    __shared__ int sd[256];
    int tid = threadIdx.x;
    int v = (tid < nbkt) ? bucketCnt[tid] : 0;
    sd[tid] = v;
    __syncthreads();
    for (int off = 1; off < 256; off <<= 1) {
        int t = (tid >= off) ? sd[tid - off] : 0;
        __syncthreads();
        sd[tid] += t;
        __syncthreads();
    }
    if (tid < nbkt) bucketStart[tid] = sd[tid] - v;
    if (tid == 0) bucketStart[nbkt] = e;
}

// p1: tile sort by superblock, contiguous run writes of packed words
__global__ __launch_bounds__(256) void k_p1(int e, const int* __restrict__ src,
                                            const int* __restrict__ dst,
                                            const int* __restrict__ bucketStart,
                                            int* __restrict__ gCursor,
                                            int* __restrict__ pkbuf) {
    __shared__ int cnt[BKTMAX], exc[BKTMAX], cur[BKTMAX], bb[BKTMAX];
    __shared__ int sd[256];
    __shared__ int stage[P1T];
    __shared__ unsigned char stgb[P1T];
    int tid = threadIdx.x;
    cnt[tid] = 0;
    __syncthreads();
    int base = blockIdx.x * P1T;
    int m = e - base; if (m > P1T) m = P1T;
    int pk8[P1T / 256];
    int b8[P1T / 256];
#pragma unroll
    for (int q = 0; q < P1T / 256; ++q) {
        int li = q * 256 + tid;
        if (li < m) {
            int d = dst[base + li];
            int s = src[base + li];
            int b = d >> 9;
            b8[q] = b;
            pk8[q] = ((d & (SBS - 1)) << USH) | s;
            atomicAdd(&cnt[b], 1);
        }
    }
    __syncthreads();
    int cv = cnt[tid];
    sd[tid] = cv;
    __syncthreads();
    for (int off = 1; off < 256; off <<= 1) {
        int t = (tid >= off) ? sd[tid - off] : 0;
        __syncthreads();
        sd[tid] += t;
        __syncthreads();
    }
    exc[tid] = sd[tid] - cv;
    cur[tid] = sd[tid] - cv;
    if (cv > 0) bb[tid] = atomicAdd(&gCursor[tid], cv);
    __syncthreads();
#pragma unroll
    for (int q = 0; q < P1T / 256; ++q) {
        int li = q * 256 + tid;
        if (li < m) {
            int b = b8[q];
            int pos = atomicAdd(&cur[b], 1);
            stage[pos] = pk8[q];
            stgb[pos] = (unsigned char)b;
        }
    }
    __syncthreads();
#pragma unroll
    for (int q = 0; q < P1T / 256; ++q) {
        int p = q * 256 + tid;
        if (p < m) {
            int b = stgb[p];
            pkbuf[bucketStart[b] + bb[b] + (p - exc[b])] = stage[p];
        }
    }
}

// p2: per-superblock counting sort -> csr [row][chunk] + bounds + dinv/xs
__global__ __launch_bounds__(256) void k_p2(int n, const int* __restrict__ bucketStart,
                                            const int* __restrict__ pkbuf,
                                            const float* __restrict__ x,
                                            int* __restrict__ csr,
                                            int* __restrict__ boundsG,
                                            float* __restrict__ dinv,
                                            float* __restrict__ xs) {
    __shared__ int cnt[SBKEYS + 1];
    __shared__ int sd[256];
    int sb = blockIdx.x, tid = threadIdx.x;
    int r0 = bucketStart[sb], r1 = bucketStart[sb + 1];
    for (int k = tid; k < SBKEYS + 1; k += 256) cnt[k] = 0;
    __syncthreads();
    // phase A: count keys
    for (int i = r0 + tid; i < r1; i += 256) {
        int w = pkbuf[i];
        int key = ((w >> USH) << 3) | ((w & UMASK) >> 14);   // dl*8 + chunk
        atomicAdd(&cnt[key], 1);
    }
    __syncthreads();
    // phase B: in-place exclusive scan (16 keys/thread)
    int base16 = tid * 16;
    int loc[16]; int s = 0;
#pragma unroll
    for (int j = 0; j < 16; ++j) { loc[j] = cnt[base16 + j]; s += loc[j]; }
    sd[tid] = s;
    __syncthreads();
    for (int off = 1; off < 256; off <<= 1) {
        int t = (tid >= off) ? sd[tid - off] : 0;
        __syncthreads();
        sd[tid] += t;
        __syncthreads();
    }
    int run = sd[tid] - s;
#pragma unroll
    for (int j = 0; j < 16; ++j) { cnt[base16 + j] = run; run += loc[j]; }
    if (tid == 255) cnt[SBKEYS] = run;
    __syncthreads();
    // bounds + dinv/xs (read cnt before phase C corrupts it)
    for (int k = tid; k < SBKEYS; k += 256) {
        int bi = sb * 16 + (k >> 8);
        boundsG[(size_t)bi * (NBIN + 1) + (k & 255)] = r0 + cnt[k];
    }
    if (tid < 16)
        boundsG[(size_t)(sb * 16 + tid) * (NBIN + 1) + NBIN] = r0 + cnt[(tid + 1) * 256];
    for (int dl = tid; dl < SBS; dl += 256) {
        int v = sb * SBS + dl;
        if (v < n) {
            int deg = cnt[dl * 8 + 8] - cnt[dl * 8] + 1;
            float di = 1.0f / sqrtf((float)deg);
            dinv[v] = di;
            xs[v] = x[v] * di;
        }
    }
    __syncthreads();
    // phase C: place (cnt doubles as cursor); block owns csr[r0..r1)
    for (int i = r0 + tid; i < r1; i += 256) {
        int w = pkbuf[i];
        int srcv = w & UMASK;
        int key = ((w >> USH) << 3) | (srcv >> 14);
        int pos = atomicAdd(&cnt[key], 1);
        csr[r0 + pos] = srcv;
    }
}

// layer 1 scalar gather, thread-per-row
__global__ __launch_bounds__(256) void k_s(int n, const int* __restrict__ boundsG,
                                           const int* __restrict__ csr,
                                           const float* __restrict__ xs,
                                           const float* __restrict__ dinv,
                                           float* __restrict__ s) {
    int v = blockIdx.x * blockDim.x + threadIdx.x;
    if (v >= n) return;
    int bi = v / NB, vi = v & (NB - 1);
    const int* B = &boundsG[(size_t)bi * (NBIN + 1)];
    int s0 = B[vi * NCHUNK];
    int s1 = B[vi * NCHUNK + NCHUNK];
    float a0 = 0.f, a1 = 0.f, a2 = 0.f, a3 = 0.f;
    int k = s0;
    for (; k + 4 <= s1; k += 4) {
        a0 += xs[csr[k]];
        a1 += xs[csr[k + 1]];
        a2 += xs[csr[k + 2]];
        a3 += xs[csr[k + 3]];
    }
    for (; k < s1; ++k) a0 += xs[csr[k]];
    s[v] = ((a0 + a1) + (a2 + a3) + xs[v]) * dinv[v];
}

// layer 1 transform: hs1 = relu(s*w1 + b1) * dinv
__global__ __launch_bounds__(256) void k_h1(int n, const float* __restrict__ s,
                                            const float* __restrict__ dinv,
                                            const float* __restrict__ w1,
                                            const float* __restrict__ b1,
                                            float* __restrict__ hs) {
    int t = blockIdx.x * blockDim.x + threadIdx.x;
    if (t >= n * 64) return;
    int i = t >> 6, j = t & 63;
    float v = fmaxf(s[i] * w1[j] + b1[j], 0.f);
    hs[t] = v * dinv[i];
}

// ---- fused chunked-gather + inline GEMM (unchanged structure) ----
#define GATHER_CORE                                                            \
    __shared__ float ws[64 * 64];                                              \
    __shared__ float rowl[4][64];                                              \
    __shared__ int bndL[NBIN + 1];                                             \
    int tid = threadIdx.x;                                                     \
    int lane = tid & 63;                                                       \
    int r = tid >> 6;                                                          \
    int v0 = blockIdx.x * NB;                                                  \
    for (int k = tid; k < 64 * 64; k += 256) ws[k] = w[k];                     \
    bndL[tid] = boundsG[(size_t)blockIdx.x * (NBIN + 1) + tid];                \
    if (tid == 0) bndL[NBIN] = boundsG[(size_t)blockIdx.x * (NBIN + 1) + NBIN];\
    float acc[RPW];                                                            \
    _Pragma("unroll")                                                          \
    for (int q = 0; q < RPW; ++q) {                                            \
        int v = v0 + q * 4 + r;                                                \
        acc[q] = (v < n) ? hs_in[(size_t)v * 64 + lane] : 0.f;                 \
    }                                                                          \
    __syncthreads();                                                           \
    for (int c = 0; c < NCHUNK; ++c) {                                         \
        _Pragma("unroll")                                                      \
        for (int t = 0; t < RPW / 2; ++t) {                                    \
            int viA = (2 * t) * 4 + r;                                         \
            int viB = (2 * t + 1) * 4 + r;                                     \
            int a0 = __builtin_amdgcn_readfirstlane(bndL[viA * NCHUNK + c]);   \
            int a1 = __builtin_amdgcn_readfirstlane(bndL[viA * NCHUNK + c + 1]);\
            int b0_ = __builtin_amdgcn_readfirstlane(bndL[viB * NCHUNK + c]);  \
            int b1_ = __builtin_amdgcn_readfirstlane(bndL[viB * NCHUNK + c + 1]);\
            int ba = a0, bb = b0_;                                             \
            while (ba < a1 || bb < b1_) {                                      \
                int remA = a1 - ba;                                            \
                int remB = b1_ - bb;                                           \
                int pa = (remA > 0) ? ba : bb;                                 \
                int pb = (remB > 0) ? bb : ba;                                 \
                int uA0 = csr[pa],     uA1 = csr[pa + 1];                      \
                int uA2 = csr[pa + 2], uA3 = csr[pa + 3];                      \
                int uB0 = csr[pb],     uB1 = csr[pb + 1];                      \
                int uB2 = csr[pb + 2], uB3 = csr[pb + 3];                      \
                float gA0 = hs_in[(size_t)uA0 * 64 + lane];                    \
                float gA1 = hs_in[(size_t)uA1 * 64 + lane];                    \
                float gA2 = hs_in[(size_t)uA2 * 64 + lane];                    \
                float gA3 = hs_in[(size_t)uA3 * 64 + lane];                    \
                float gB0 = hs_in[(size_t)uB0 * 64 + lane];                    \
                float gB1 = hs_in[(size_t)uB1 * 64 + lane];                    \
                float gB2 = hs_in[(size_t)uB2 * 64 + lane];                    \
                float gB3 = hs_in[(size_t)uB3 * 64 + lane];                    \
                if (remA >= 4) acc[2 * t] += (gA0 + gA1) + (gA2 + gA3);        \
                else if (remA > 0) {                                           \
                    acc[2 * t] += gA0;                                         \
                    if (remA > 1) acc[2 * t] += gA1;                           \
                    if (remA > 2) acc[2 * t] += gA2;                           \
                }                                                              \
                if (remB >= 4) acc[2 * t + 1] += (gB0 + gB1) + (gB2 + gB3);    \
                else if (remB > 0) {                                           \
                    acc[2 * t + 1] += gB0;                                     \
                    if (remB > 1) acc[2 * t + 1] += gB1;                       \
                    if (remB > 2) acc[2 * t + 1] += gB2;                       \
                }                                                              \
                ba += 4; bb += 4;                                              \
            }                                                                  \
        }                                                                      \
        __syncthreads();                                                       \
    }

__global__ __launch_bounds__(256, 8) void k_gg_mid(int n,
                                                   const int* __restrict__ boundsG,
                                                   const int* __restrict__ csr,
                                                   const float* __restrict__ hs_in,
                                                   const float* __restrict__ dinv,
                                                   const float* __restrict__ w,
                                                   const float* __restrict__ b,
                                                   float* __restrict__ hs_out) {
    GATHER_CORE
    float breg = b[lane];
#pragma unroll 1
    for (int q = 0; q < RPW; ++q) {
        int v = v0 + q * 4 + r;
        if (v >= n) continue;
        float dv = dinv[v];
        rowl[r][lane] = acc[q] * dv;
        float o = breg;
#pragma unroll
        for (int k = 0; k < 64; ++k) o += rowl[r][k] * ws[k * 64 + lane];
        hs_out[(size_t)v * 64 + lane] = fmaxf(o, 0.f) * dv;
    }
}

__global__ __launch_bounds__(256, 8) void k_gg_final(int n,
                                                     const int* __restrict__ boundsG,
                                                     const int* __restrict__ csr,
                                                     const float* __restrict__ hs_in,
                                                     const float* __restrict__ dinv,
                                                     const float* __restrict__ w,
                                                     const float* __restrict__ b,
                                                     const float* __restrict__ fcw,
                                                     float* __restrict__ dots) {
    GATHER_CORE
    float breg = b[lane];
    float freg = fcw[lane];
#pragma unroll 1
    for (int q = 0; q < RPW; ++q) {
        int v = v0 + q * 4 + r;
        if (v >= n) continue;
        float dv = dinv[v];
        rowl[r][lane] = acc[q] * dv;
        float o = breg;
#pragma unroll
        for (int k = 0; k < 64; ++k) o += rowl[r][k] * ws[k * 64 + lane];
        float val = fmaxf(o, 0.f) * freg;
#pragma unroll
        for (int m = 32; m > 0; m >>= 1) val += __shfl_xor(val, m, 64);
        if (lane == 0) dots[v] = val;
    }
}

// pooled accumulation: LDS-binned segmented reduce over sorted batch
__global__ __launch_bounds__(256) void k_pool(int n, const float* __restrict__ dots,
                                              const int* __restrict__ batch,
                                              float* __restrict__ gsum,
                                              float* __restrict__ gcnt) {
    __shared__ float ls[64], lc[64];
    __shared__ int gmin_s;
    int tid = threadIdx.x;
    int i0 = blockIdx.x * 1024;
    if (tid == 0) gmin_s = batch[i0];
    if (tid < 64) { ls[tid] = 0.f; lc[tid] = 0.f; }
    __syncthreads();
    int gmin = gmin_s;
#pragma unroll
    for (int c = 0; c < 4; ++c) {
        int i = i0 + c * 256 + tid;
        if (i < n) {
            int g = batch[i];
            float d = dots[i];
            int rr = g - gmin;
            if (rr < 64) {
                atomicAdd(&ls[rr], d);
                atomicAdd(&lc[rr], 1.f);
            } else {
                atomicAdd(&gsum[g], d);
                atomicAdd(&gcnt[g], 1.f);
            }
        }
    }
    __syncthreads();
    if (tid < 64 && lc[tid] != 0.f) {
        atomicAdd(&gsum[gmin + tid], ls[tid]);
        atomicAdd(&gcnt[gmin + tid], lc[tid]);
    }
}

__global__ __launch_bounds__(256) void k_out(int g, const float* __restrict__ gsum,
                                             const float* __restrict__ gcnt,
                                             const float* __restrict__ fcb,
                                             float* __restrict__ out) {
    int i = blockIdx.x * blockDim.x + threadIdx.x;
    if (i < g) out[i] = gsum[i] / fmaxf(gcnt[i], 1.f) + fcb[0];
}

extern "C" void kernel_launch(void* const* d_in, const int* in_sizes, int n_in,
                              void* d_out, int out_size, void* d_ws, size_t ws_size,
                              hipStream_t stream) {
    const float* x    = (const float*)d_in[0];
    const int*   ei   = (const int*)d_in[1];
    const int*   batch= (const int*)d_in[2];
    const float* w1   = (const float*)d_in[3];
    const float* b1   = (const float*)d_in[4];
    const float* w2   = (const float*)d_in[5];
    const float* b2   = (const float*)d_in[6];
    const float* w3   = (const float*)d_in[7];
    const float* b3   = (const float*)d_in[8];
    const float* fcw  = (const float*)d_in[9];
    const float* fcb  = (const float*)d_in[10];
    float* out = (float*)d_out;

    const int N = in_sizes[0];           // needs N <= 131072 (17-bit packing)
    const int E = in_sizes[1] / 2;
    const int G = out_size;
    const int H = 64;
    const int nbkt = (N + SBS - 1) / SBS;        // 196 superblocks
    const int NBLK = (N + NB - 1) / NB;          // 3125 gather blocks
    const int NBLKP = nbkt * 16;                 // padded bounds rows (3136)

    const int* src = ei;
    const int* dst = ei + E;

    char* p = (char*)d_ws;
    int*   bucketCnt   = (int*)p; p += WS_ALIGN(sizeof(int) * BKTMAX);
    int*   bucketStart = (int*)p; p += WS_ALIGN(sizeof(int) * (BKTMAX + 1));
    int*   gCursor     = (int*)p; p += WS_ALIGN(sizeof(int) * BKTMAX);
    int*   pkbuf       = (int*)p; p += WS_ALIGN(sizeof(int) * (size_t)E);
    int*   csr         = (int*)p; p += WS_ALIGN(sizeof(int) * ((size_t)E + 4));
    int*   boundsG     = (int*)p; p += WS_ALIGN(sizeof(int) * (size_t)NBLKP * (NBIN + 1));
    float* dinv        = (float*)p; p += WS_ALIGN(sizeof(float) * N);
    float* xs          = (float*)p; p += WS_ALIGN(sizeof(float) * N);
    float* sbuf        = (float*)p; p += WS_ALIGN(sizeof(float) * N);
    float* bufA        = (float*)p; p += WS_ALIGN(sizeof(float) * (size_t)N * H);
    float* bufB        = (float*)p; p += WS_ALIGN(sizeof(float) * (size_t)N * H);
    float* dots        = (float*)p; p += WS_ALIGN(sizeof(float) * N);
    float* gsum        = (float*)p; p += WS_ALIGN(sizeof(float) * G);
    float* gcnt        = (float*)p; p += WS_ALIGN(sizeof(float) * G);

    const int B = 256;
    int gridZ    = ((G > BKTMAX ? G : BKTMAX) + B - 1) / B;
    int gridT    = (E + P1T - 1) / P1T;          // 1563 tiles
    int gridRow  = (N + B - 1) / B;
    int gridNH   = (N * H + B - 1) / B;
    int gridG    = (G + B - 1) / B;
    int gridPool = (N + 1023) / 1024;

    k_zero<<<gridZ, B, 0, stream>>>(G, E, bucketCnt, gCursor, csr, gsum, gcnt);
    k_cnt1<<<gridT, B, 0, stream>>>(E, dst, bucketCnt);
    k_scanB<<<1, B, 0, stream>>>(nbkt, E, bucketCnt, bucketStart);
    k_p1<<<gridT, B, 0, stream>>>(E, src, dst, bucketStart, gCursor, pkbuf);
    k_p2<<<nbkt, B, 0, stream>>>(N, bucketStart, pkbuf, x, csr, boundsG, dinv, xs);
    // layer 1 (rank-1)
    k_s<<<gridRow, B, 0, stream>>>(N, boundsG, csr, xs, dinv, sbuf);
    k_h1<<<gridNH, B, 0, stream>>>(N, sbuf, dinv, w1, b1, bufA);
    // layer 2: fused gather + GEMM(w2) -> bufB
    k_gg_mid<<<NBLK, B, 0, stream>>>(N, boundsG, csr, bufA, dinv, w2, b2, bufB);
    // layer 3: fused gather + GEMM(w3) + fc dot -> dots
    k_gg_final<<<NBLK, B, 0, stream>>>(N, boundsG, csr, bufB, dinv, w3, b3, fcw, dots);
    // pooling + head
    k_pool<<<gridPool, B, 0, stream>>>(N, dots, batch, gsum, gcnt);
    k_out<<<gridG, B, 0, stream>>>(G, gsum, gcnt, fcb, out);
}